// Round 18
// baseline (38.657 us; speedup 1.0000x reference)
//
#include <hip/hip_runtime.h>
#include <math.h>

// ChamferLoss via matrix cores — v_mfma_f32_32x32x16_f16 (K=16), PACKED:
// A-fragment lanes 0..31 (k=0..7)  = rows of tile 2T   (emb in e=0..4)
// A-fragment lanes 32..63 (k=8..15)= rows of tile 2T+1 (emb in e=0..4)
// B-frag bfLO: k=0..4 = (x,y,z,-|b|^2/2,1), k>=8 zero  -> C = tile2T   x col
// B-frag bfHI: k=8..12 = same, k<8 zero               -> C = tile2T+1 x col
// C[i][j] = a.b - (|a|^2+|b|^2)/2 = -dist^2/2 ; min dist^2 = -2 max C.
//
// R18: REGISTER-PRESSURE experiment. R16's counters (VGPR=28, 2x slower at
// equal work) implicate AGPR allocation of C + v_accvgpr_read laundering as
// the dominant hidden VALU cost. BFRAGS=1 keeps the live set ~75 regs, well
// under the 128-reg (512,4) budget, so C can stay in arch VGPRs.
// Fold: accv[i] = fmax(accv[i], fmax(Ca[i],Cb[i])) — max3-fusable,
// 1 instr per 2 C-elements, exact (same column, different rows).

typedef _Float16 half8 __attribute__((ext_vector_type(8)));
typedef float floatx16 __attribute__((ext_vector_type(16)));

constexpr int B_ = 64;
constexpr int N_ = 2048;
constexpr int NT = N_ / 32;        // 64 row-tiles
constexpr int NPAIR = NT / 2;      // 32 packed tile-pairs
constexpr int BLOCK = 512;         // 8 waves
constexpr int WPB = 8;
constexpr int IBLK = NT / WPB;     // 8 blocks along col-tile axis (BFRAGS=1)
constexpr int NBLK = IBLK * B_ * 2;         // 1024 partials
constexpr int RBLOCK = 1024;

__global__ __launch_bounds__(BLOCK, 4) void chamfer_mfma_kernel(
    const float* __restrict__ p, const float* __restrict__ q,
    float* __restrict__ partials)
{
    __shared__ half8 Aarr[N_];            // 32 KB: Aarr[j] = emb(row j)
    __shared__ float wsum[WPB];

    const int dir = blockIdx.z;            // 0: A=q,B=p ; 1: A=p,B=q
    const int b   = blockIdx.y;
    const float4* rowsA = (const float4*)((dir == 0 ? q : p) + (size_t)b * N_ * 4);
    const float4* colsB = (const float4*)((dir == 0 ? p : q) + (size_t)b * N_ * 4);

    const int lane = threadIdx.x & 63;
    const int wid  = threadIdx.x >> 6;

    // Issue the B column load early; its latency hides under the A-build.
    float4 vB = colsB[(blockIdx.x * WPB + wid) * 32 + (lane & 31)];

    // Build the A-embedding table: Aarr[j] = (x,y,z,1,-|a|^2/2,0,0,0).
    for (int j = threadIdx.x; j < N_; j += BLOCK) {
        float4 v = rowsA[j];
        _Float16 x = (_Float16)v.y, y = (_Float16)v.z, z = (_Float16)v.w;
        float xf = (float)x, yf = (float)y, zf = (float)z;
        float sq = fmaf(xf, xf, fmaf(yf, yf, zf * zf));
        half8 lo;
        lo[0] = x; lo[1] = y; lo[2] = z; lo[3] = (_Float16)1.0f;
        lo[4] = (_Float16)(-0.5f * sq);
        lo[5] = (_Float16)0.0f; lo[6] = (_Float16)0.0f; lo[7] = (_Float16)0.0f;
        Aarr[j] = lo;
    }

    // One col-tile per wave, LO (k=0..7 lanes) and HI (k=8..15) variants.
    half8 bfLO, bfHI;
    {
        _Float16 x = (_Float16)vB.y, y = (_Float16)vB.z, z = (_Float16)vB.w;
        float xf = (float)x, yf = (float)y, zf = (float)z;
        float sq = fmaf(xf, xf, fmaf(yf, yf, zf * zf));
#pragma unroll
        for (int e = 0; e < 8; ++e) { bfLO[e] = (_Float16)0.0f; bfHI[e] = (_Float16)0.0f; }
        if (lane < 32) {
            bfLO[0] = x; bfLO[1] = y; bfLO[2] = z;
            bfLO[3] = (_Float16)(-0.5f * sq);
            bfLO[4] = (_Float16)1.0f;
        } else {
            bfHI[0] = x; bfHI[1] = y; bfHI[2] = z;
            bfHI[3] = (_Float16)(-0.5f * sq);
            bfHI[4] = (_Float16)1.0f;
        }
    }
    __syncthreads();

    floatx16 zero;
#pragma unroll
    for (int i = 0; i < 16; ++i) zero[i] = 0.0f;

    floatx16 accv;
#pragma unroll
    for (int i = 0; i < 16; ++i) accv[i] = -3.4e38f;

    // Sweep 32 tile-pairs: 1 ds_read_b128 -> 2 MFMAs -> 16 max3 folds.
    for (int T = 0; T < NPAIR; ++T) {
        half8 af = Aarr[T * 64 + lane];
        floatx16 Ca = __builtin_amdgcn_mfma_f32_32x32x16_f16(af, bfLO, zero, 0, 0, 0);
        floatx16 Cb = __builtin_amdgcn_mfma_f32_32x32x16_f16(af, bfHI, zero, 0, 0, 0);
#pragma unroll
        for (int i = 0; i < 16; ++i)
            accv[i] = fmaxf(accv[i], fmaxf(Ca[i], Cb[i]));
    }

    // 16 -> 1 per lane, then combine the two lane-halves (same column).
    float cmx = accv[0];
#pragma unroll
    for (int i = 1; i < 16; ++i) cmx = fmaxf(cmx, accv[i]);
    cmx = fmaxf(cmx, __shfl_xor(cmx, 32, 64));

    float local = sqrtf(fmaxf(-2.0f * cmx, 0.0f) + 1e-16f);

#pragma unroll
    for (int off = 32; off > 0; off >>= 1)
        local += __shfl_xor(local, off, 64);

    if (lane == 0) wsum[wid] = local;
    __syncthreads();
    if (threadIdx.x == 0) {
        float s = 0.0f;
#pragma unroll
        for (int w = 0; w < WPB; ++w) s += wsum[w];
        // 0.5 chamfer factor * 0.5 lane-dup; plain store, no init needed.
        partials[(blockIdx.z * B_ + blockIdx.y) * IBLK + blockIdx.x] = 0.25f * s;
    }
}

__global__ __launch_bounds__(RBLOCK) void chamfer_reduce_kernel(
    const float* __restrict__ partials, float* __restrict__ out)
{
    float v = partials[threadIdx.x];
#pragma unroll
    for (int off = 32; off > 0; off >>= 1)
        v += __shfl_xor(v, off, 64);

    __shared__ float wsum[RBLOCK / 64];
    if ((threadIdx.x & 63) == 0) wsum[threadIdx.x >> 6] = v;
    __syncthreads();
    if (threadIdx.x == 0) {
        float s = 0.0f;
#pragma unroll
        for (int w = 0; w < RBLOCK / 64; ++w) s += wsum[w];
        out[0] = s;
    }
}

extern "C" void kernel_launch(void* const* d_in, const int* in_sizes, int n_in,
                              void* d_out, int out_size, void* d_ws, size_t ws_size,
                              hipStream_t stream) {
    const float* p = (const float*)d_in[0];
    const float* q = (const float*)d_in[1];
    float* out = (float*)d_out;
    float* partials = (float*)d_ws;

    dim3 grid(IBLK, B_, 2);                 // 8 x 64 x 2 = 1024 blocks
    chamfer_mfma_kernel<<<grid, BLOCK, 0, stream>>>(p, q, partials);
    chamfer_reduce_kernel<<<1, RBLOCK, 0, stream>>>(partials, out);
}

// Round 19
// 22.401 us; speedup vs baseline: 1.7257x; 1.7257x over previous
//
#include <hip/hip_runtime.h>
#include <math.h>

// ChamferLoss via matrix cores — v_mfma_f32_32x32x16_f16 (K=16), PACKED:
// A-fragment lanes 0..31 (k=0..7)  = rows of tile 2T   (emb in e=0..4)
// A-fragment lanes 32..63 (k=8..15)= rows of tile 2T+1 (emb in e=0..4)
// B-frag bfLO: k=0..4 = (x,y,z,-|b|^2/2,1), k>=8 zero  -> C = tile2T   x col
// B-frag bfHI: k=8..12 = same, k<8 zero               -> C = tile2T+1 x col
// ONE full-width ds_read_b128 feeds 4 MFMAs (2 row-tiles x 2 col-tiles).
// C[i][j] = a.b - (|a|^2+|b|^2)/2 = -dist^2/2 ; min dist^2 = -2 max C.
//
// R19: REGISTER-BUDGET experiment. R13/R16/R18 counters show arch-VGPR
// 28-44 and ~115 VALU instr/iter (static fold = ~64): the compiler puts
// MFMA C-tiles + accv in AGPRs under the 128-reg (512,4) budget and pays
// v_accvgpr_read/write laundering on every fold. launch_bounds(512,2)
// gives a 256-reg budget so the ~100-reg live set fits in ArchVGPRs.
// Per-SIMD work is unchanged (4096 waves / 1024 SIMDs); fold(T) is
// independent of MFMA(T+1), so 2 resident waves still co-fill both pipes.

typedef _Float16 half8 __attribute__((ext_vector_type(8)));
typedef float floatx16 __attribute__((ext_vector_type(16)));

constexpr int B_ = 64;
constexpr int N_ = 2048;
constexpr int NT = N_ / 32;        // 64 row-tiles
constexpr int NPAIR = NT / 2;      // 32 packed tile-pairs
constexpr int BLOCK = 512;         // 8 waves
constexpr int WPB = 8;
constexpr int BFRAGS = 2;          // col-tiles per wave
constexpr int IBLK = NT / (WPB * BFRAGS);   // 4 blocks along col-tile axis
constexpr int NBLK = IBLK * B_ * 2;         // 512 partials

__global__ __launch_bounds__(BLOCK, 2) void chamfer_mfma_kernel(
    const float* __restrict__ p, const float* __restrict__ q,
    float* __restrict__ partials)
{
    __shared__ half8 Aarr[N_];            // 32 KB: Aarr[j] = emb(row j)
    __shared__ float wsum[WPB];

    const int dir = blockIdx.z;            // 0: A=q,B=p ; 1: A=p,B=q
    const int b   = blockIdx.y;
    const float4* rowsA = (const float4*)((dir == 0 ? q : p) + (size_t)b * N_ * 4);
    const float4* colsB = (const float4*)((dir == 0 ? p : q) + (size_t)b * N_ * 4);

    // Build the A-embedding table: Aarr[j] = (x,y,z,1,-|a|^2/2,0,0,0).
    for (int j = threadIdx.x; j < N_; j += BLOCK) {
        float4 v = rowsA[j];
        _Float16 x = (_Float16)v.y, y = (_Float16)v.z, z = (_Float16)v.w;
        float xf = (float)x, yf = (float)y, zf = (float)z;
        float sq = fmaf(xf, xf, fmaf(yf, yf, zf * zf));
        half8 lo;
        lo[0] = x; lo[1] = y; lo[2] = z; lo[3] = (_Float16)1.0f;
        lo[4] = (_Float16)(-0.5f * sq);
        lo[5] = (_Float16)0.0f; lo[6] = (_Float16)0.0f; lo[7] = (_Float16)0.0f;
        Aarr[j] = lo;
    }

    // Per-wave B fragments: col-tiles 2W, 2W+1; each as LO (k=0..7 lanes)
    // and HI (k=8..15 lanes) variants.
    const int lane = threadIdx.x & 63;
    const int wid  = threadIdx.x >> 6;
    const int W    = blockIdx.x * WPB + wid;
    half8 bfLO[BFRAGS], bfHI[BFRAGS];
#pragma unroll
    for (int t = 0; t < BFRAGS; ++t) {
        float4 v = colsB[(W * BFRAGS + t) * 32 + (lane & 31)];
        _Float16 x = (_Float16)v.y, y = (_Float16)v.z, z = (_Float16)v.w;
        float xf = (float)x, yf = (float)y, zf = (float)z;
        float sq = fmaf(xf, xf, fmaf(yf, yf, zf * zf));
#pragma unroll
        for (int e = 0; e < 8; ++e) { bfLO[t][e] = (_Float16)0.0f; bfHI[t][e] = (_Float16)0.0f; }
        if (lane < 32) {
            bfLO[t][0] = x; bfLO[t][1] = y; bfLO[t][2] = z;
            bfLO[t][3] = (_Float16)(-0.5f * sq);
            bfLO[t][4] = (_Float16)1.0f;
        } else {
            bfHI[t][0] = x; bfHI[t][1] = y; bfHI[t][2] = z;
            bfHI[t][3] = (_Float16)(-0.5f * sq);
            bfHI[t][4] = (_Float16)1.0f;
        }
    }
    __syncthreads();

    floatx16 zero;
#pragma unroll
    for (int i = 0; i < 16; ++i) zero[i] = 0.0f;

    floatx16 accv0, accv1;
#pragma unroll
    for (int i = 0; i < 16; ++i) { accv0[i] = -3.4e38f; accv1[i] = -3.4e38f; }

    // Sweep 32 tile-pairs: 1 full-width ds_read_b128 -> 4 MFMAs.
    // Fold each col-tile's pair of C's immediately (2 C-tiles live max).
    for (int T = 0; T < NPAIR; ++T) {
        half8 af = Aarr[T * 64 + lane];
        {
            floatx16 Ca = __builtin_amdgcn_mfma_f32_32x32x16_f16(af, bfLO[0], zero, 0, 0, 0);
            floatx16 Cb = __builtin_amdgcn_mfma_f32_32x32x16_f16(af, bfHI[0], zero, 0, 0, 0);
#pragma unroll
            for (int i = 0; i < 16; ++i)
                accv0[i] = fmaxf(accv0[i], fmaxf(Ca[i], Cb[i]));
        }
        {
            floatx16 Ca = __builtin_amdgcn_mfma_f32_32x32x16_f16(af, bfLO[1], zero, 0, 0, 0);
            floatx16 Cb = __builtin_amdgcn_mfma_f32_32x32x16_f16(af, bfHI[1], zero, 0, 0, 0);
#pragma unroll
            for (int i = 0; i < 16; ++i)
                accv1[i] = fmaxf(accv1[i], fmaxf(Ca[i], Cb[i]));
        }
    }

    // Reduce the two 16-element accumulators to scalars (once per wave).
    float cmx0 = accv0[0], cmx1 = accv1[0];
#pragma unroll
    for (int i = 1; i < 16; ++i) {
        cmx0 = fmaxf(cmx0, accv0[i]);
        cmx1 = fmaxf(cmx1, accv1[i]);
    }

    // Combine the two lane-halves (each holds half the rows per column).
    cmx0 = fmaxf(cmx0, __shfl_xor(cmx0, 32, 64));
    cmx1 = fmaxf(cmx1, __shfl_xor(cmx1, 32, 64));

    float local = sqrtf(fmaxf(-2.0f * cmx0, 0.0f) + 1e-16f)
                + sqrtf(fmaxf(-2.0f * cmx1, 0.0f) + 1e-16f);

#pragma unroll
    for (int off = 32; off > 0; off >>= 1)
        local += __shfl_xor(local, off, 64);

    if (lane == 0) wsum[wid] = local;
    __syncthreads();
    if (threadIdx.x == 0) {
        float s = 0.0f;
#pragma unroll
        for (int w = 0; w < WPB; ++w) s += wsum[w];
        // 0.5 chamfer factor * 0.5 lane-dup; plain store, no init needed.
        partials[(blockIdx.z * B_ + blockIdx.y) * IBLK + blockIdx.x] = 0.25f * s;
    }
}

__global__ __launch_bounds__(NBLK) void chamfer_reduce_kernel(
    const float* __restrict__ partials, float* __restrict__ out)
{
    float v = partials[threadIdx.x];
#pragma unroll
    for (int off = 32; off > 0; off >>= 1)
        v += __shfl_xor(v, off, 64);

    __shared__ float wsum[NBLK / 64];
    if ((threadIdx.x & 63) == 0) wsum[threadIdx.x >> 6] = v;
    __syncthreads();
    if (threadIdx.x == 0) {
        float s = 0.0f;
#pragma unroll
        for (int w = 0; w < NBLK / 64; ++w) s += wsum[w];
        out[0] = s;
    }
}

extern "C" void kernel_launch(void* const* d_in, const int* in_sizes, int n_in,
                              void* d_out, int out_size, void* d_ws, size_t ws_size,
                              hipStream_t stream) {
    const float* p = (const float*)d_in[0];
    const float* q = (const float*)d_in[1];
    float* out = (float*)d_out;
    float* partials = (float*)d_ws;

    dim3 grid(IBLK, B_, 2);                 // 4 x 64 x 2 = 512 blocks
    chamfer_mfma_kernel<<<grid, BLOCK, 0, stream>>>(p, q, partials);
    chamfer_reduce_kernel<<<1, NBLK, 0, stream>>>(partials, out);
}

// Round 20
// 22.307 us; speedup vs baseline: 1.7330x; 1.0042x over previous
//
#include <hip/hip_runtime.h>
#include <math.h>

// ChamferLoss via matrix cores — v_mfma_f32_32x32x16_f16 (K=16), PACKED:
// A-fragment lanes 0..31 (k=0..7)  = rows of tile 2T   (emb in e=0..4)
// A-fragment lanes 32..63 (k=8..15)= rows of tile 2T+1 (emb in e=0..4)
// B-frag bfLO: k=0..4 = (x,y,z,-|b|^2/2,1), k>=8 zero  -> C = tile2T   x col
// B-frag bfHI: k=8..12 = same, k<8 zero               -> C = tile2T+1 x col
// ONE full-width ds_read_b128 feeds 4 MFMAs (2 row-tiles x 2 col-tiles).
// C[i][j] = a.b - (|a|^2+|b|^2)/2 = -dist^2/2 ; min dist^2 = -2 max C.
//
// R20: pipeline-under-256-budget. R11/R14's pipelining failed under the
// 128-reg (512,4) cap (AGPR-split / spill); with (512,2) the 4-live-C
// grouped iteration (~120 regs) fits in arch VGPRs. Branch-free af
// prefetch (table padded by one tile; the pad is read but never folded)
// takes the ds_read off the critical path; 4 back-to-back MFMAs stream
// the matrix pipe while the previous folds run on the VALU.

typedef _Float16 half8 __attribute__((ext_vector_type(8)));
typedef float floatx16 __attribute__((ext_vector_type(16)));

constexpr int B_ = 64;
constexpr int N_ = 2048;
constexpr int NT = N_ / 32;        // 64 row-tiles
constexpr int NPAIR = NT / 2;      // 32 packed tile-pairs
constexpr int BLOCK = 512;         // 8 waves
constexpr int WPB = 8;
constexpr int BFRAGS = 2;          // col-tiles per wave
constexpr int IBLK = NT / (WPB * BFRAGS);   // 4 blocks along col-tile axis
constexpr int NBLK = IBLK * B_ * 2;         // 512 partials

__global__ __launch_bounds__(BLOCK, 2) void chamfer_mfma_kernel(
    const float* __restrict__ p, const float* __restrict__ q,
    float* __restrict__ partials)
{
    __shared__ half8 Aarr[N_ + 64];       // 33 KB: +1 pad tile for prefetch
    __shared__ float wsum[WPB];

    const int dir = blockIdx.z;            // 0: A=q,B=p ; 1: A=p,B=q
    const int b   = blockIdx.y;
    const float4* rowsA = (const float4*)((dir == 0 ? q : p) + (size_t)b * N_ * 4);
    const float4* colsB = (const float4*)((dir == 0 ? p : q) + (size_t)b * N_ * 4);

    // Build the A-embedding table: Aarr[j] = (x,y,z,1,-|a|^2/2,0,0,0).
    for (int j = threadIdx.x; j < N_; j += BLOCK) {
        float4 v = rowsA[j];
        _Float16 x = (_Float16)v.y, y = (_Float16)v.z, z = (_Float16)v.w;
        float xf = (float)x, yf = (float)y, zf = (float)z;
        float sq = fmaf(xf, xf, fmaf(yf, yf, zf * zf));
        half8 lo;
        lo[0] = x; lo[1] = y; lo[2] = z; lo[3] = (_Float16)1.0f;
        lo[4] = (_Float16)(-0.5f * sq);
        lo[5] = (_Float16)0.0f; lo[6] = (_Float16)0.0f; lo[7] = (_Float16)0.0f;
        Aarr[j] = lo;
    }

    // Per-wave B fragments: col-tiles 2W, 2W+1; each as LO (k=0..7 lanes)
    // and HI (k=8..15 lanes) variants.
    const int lane = threadIdx.x & 63;
    const int wid  = threadIdx.x >> 6;
    const int W    = blockIdx.x * WPB + wid;
    half8 bfLO[BFRAGS], bfHI[BFRAGS];
#pragma unroll
    for (int t = 0; t < BFRAGS; ++t) {
        float4 v = colsB[(W * BFRAGS + t) * 32 + (lane & 31)];
        _Float16 x = (_Float16)v.y, y = (_Float16)v.z, z = (_Float16)v.w;
        float xf = (float)x, yf = (float)y, zf = (float)z;
        float sq = fmaf(xf, xf, fmaf(yf, yf, zf * zf));
#pragma unroll
        for (int e = 0; e < 8; ++e) { bfLO[t][e] = (_Float16)0.0f; bfHI[t][e] = (_Float16)0.0f; }
        if (lane < 32) {
            bfLO[t][0] = x; bfLO[t][1] = y; bfLO[t][2] = z;
            bfLO[t][3] = (_Float16)(-0.5f * sq);
            bfLO[t][4] = (_Float16)1.0f;
        } else {
            bfHI[t][0] = x; bfHI[t][1] = y; bfHI[t][2] = z;
            bfHI[t][3] = (_Float16)(-0.5f * sq);
            bfHI[t][4] = (_Float16)1.0f;
        }
    }
    __syncthreads();

    floatx16 zero;
#pragma unroll
    for (int i = 0; i < 16; ++i) zero[i] = 0.0f;

    floatx16 accv0, accv1;
#pragma unroll
    for (int i = 0; i < 16; ++i) { accv0[i] = -3.4e38f; accv1[i] = -3.4e38f; }

    // Pipelined sweep: prefetch af(T+1) (pad read at T=31, never folded);
    // 4 grouped MFMAs stream the matrix pipe, folds overlap on the VALU.
    half8 af = Aarr[lane];
#pragma unroll 1
    for (int T = 0; T < NPAIR; ++T) {
        half8 afn = Aarr[(T + 1) * 64 + lane];   // branch-free prefetch
        floatx16 Ca0 = __builtin_amdgcn_mfma_f32_32x32x16_f16(af, bfLO[0], zero, 0, 0, 0);
        floatx16 Cb0 = __builtin_amdgcn_mfma_f32_32x32x16_f16(af, bfHI[0], zero, 0, 0, 0);
        floatx16 Ca1 = __builtin_amdgcn_mfma_f32_32x32x16_f16(af, bfLO[1], zero, 0, 0, 0);
        floatx16 Cb1 = __builtin_amdgcn_mfma_f32_32x32x16_f16(af, bfHI[1], zero, 0, 0, 0);
#pragma unroll
        for (int i = 0; i < 16; ++i)
            accv0[i] = fmaxf(accv0[i], fmaxf(Ca0[i], Cb0[i]));
#pragma unroll
        for (int i = 0; i < 16; ++i)
            accv1[i] = fmaxf(accv1[i], fmaxf(Ca1[i], Cb1[i]));
        af = afn;
    }

    // Reduce the two 16-element accumulators to scalars (once per wave).
    float cmx0 = accv0[0], cmx1 = accv1[0];
#pragma unroll
    for (int i = 1; i < 16; ++i) {
        cmx0 = fmaxf(cmx0, accv0[i]);
        cmx1 = fmaxf(cmx1, accv1[i]);
    }

    // Combine the two lane-halves (each holds half the rows per column).
    cmx0 = fmaxf(cmx0, __shfl_xor(cmx0, 32, 64));
    cmx1 = fmaxf(cmx1, __shfl_xor(cmx1, 32, 64));

    float local = sqrtf(fmaxf(-2.0f * cmx0, 0.0f) + 1e-16f)
                + sqrtf(fmaxf(-2.0f * cmx1, 0.0f) + 1e-16f);

#pragma unroll
    for (int off = 32; off > 0; off >>= 1)
        local += __shfl_xor(local, off, 64);

    if (lane == 0) wsum[wid] = local;
    __syncthreads();
    if (threadIdx.x == 0) {
        float s = 0.0f;
#pragma unroll
        for (int w = 0; w < WPB; ++w) s += wsum[w];
        // 0.5 chamfer factor * 0.5 lane-dup; plain store, no init needed.
        partials[(blockIdx.z * B_ + blockIdx.y) * IBLK + blockIdx.x] = 0.25f * s;
    }
}

__global__ __launch_bounds__(NBLK) void chamfer_reduce_kernel(
    const float* __restrict__ partials, float* __restrict__ out)
{
    float v = partials[threadIdx.x];
#pragma unroll
    for (int off = 32; off > 0; off >>= 1)
        v += __shfl_xor(v, off, 64);

    __shared__ float wsum[NBLK / 64];
    if ((threadIdx.x & 63) == 0) wsum[threadIdx.x >> 6] = v;
    __syncthreads();
    if (threadIdx.x == 0) {
        float s = 0.0f;
#pragma unroll
        for (int w = 0; w < NBLK / 64; ++w) s += wsum[w];
        out[0] = s;
    }
}

extern "C" void kernel_launch(void* const* d_in, const int* in_sizes, int n_in,
                              void* d_out, int out_size, void* d_ws, size_t ws_size,
                              hipStream_t stream) {
    const float* p = (const float*)d_in[0];
    const float* q = (const float*)d_in[1];
    float* out = (float*)d_out;
    float* partials = (float*)d_ws;

    dim3 grid(IBLK, B_, 2);                 // 4 x 64 x 2 = 512 blocks
    chamfer_mfma_kernel<<<grid, BLOCK, 0, stream>>>(p, q, partials);
    chamfer_reduce_kernel<<<1, NBLK, 0, stream>>>(partials, out);
}

// Round 21
// 22.279 us; speedup vs baseline: 1.7351x; 1.0012x over previous
//
#include <hip/hip_runtime.h>
#include <math.h>

// ChamferLoss via matrix cores — v_mfma_f32_32x32x16_f16 (K=16), PACKED:
// A-fragment lanes 0..31 (k=0..7)  = rows of tile 2T   (emb in e=0..4)
// A-fragment lanes 32..63 (k=8..15)= rows of tile 2T+1 (emb in e=0..4)
// B-frag bfLO: k=0..4 = (x,y,z,-|b|^2/2,1), k>=8 zero  -> C = tile2T   x col
// B-frag bfHI: k=8..12 = same, k<8 zero               -> C = tile2T+1 x col
// ONE full-width ds_read_b128 feeds 4 MFMAs (2 row-tiles x 2 col-tiles).
// C[i][j] = a.b - (|a|^2+|b|^2)/2 = -dist^2/2 ; min dist^2 = -2 max C.
//
// R21: T5 experiment — s_setprio(1) around the 4-MFMA cluster. Our waves
// run with NO in-loop barrier (independent phases, like the attn case
// where T5 gave +4-7%; null only for barrier-lockstep GEMM). Priority
// boost during the MFMA burst lets the scheduler overlap other waves'
// VALU folds with this wave's matrix work.

typedef _Float16 half8 __attribute__((ext_vector_type(8)));
typedef float floatx16 __attribute__((ext_vector_type(16)));

constexpr int B_ = 64;
constexpr int N_ = 2048;
constexpr int NT = N_ / 32;        // 64 row-tiles
constexpr int NPAIR = NT / 2;      // 32 packed tile-pairs
constexpr int BLOCK = 512;         // 8 waves
constexpr int WPB = 8;
constexpr int BFRAGS = 2;          // col-tiles per wave
constexpr int IBLK = NT / (WPB * BFRAGS);   // 4 blocks along col-tile axis
constexpr int NBLK = IBLK * B_ * 2;         // 512 partials
constexpr int RBLOCK = 256;

__global__ __launch_bounds__(BLOCK, 2) void chamfer_mfma_kernel(
    const float* __restrict__ p, const float* __restrict__ q,
    float* __restrict__ partials)
{
    __shared__ half8 Aarr[N_ + 64];       // 33 KB: +1 pad tile for prefetch
    __shared__ float wsum[WPB];

    const int dir = blockIdx.z;            // 0: A=q,B=p ; 1: A=p,B=q
    const int b   = blockIdx.y;
    const float4* rowsA = (const float4*)((dir == 0 ? q : p) + (size_t)b * N_ * 4);
    const float4* colsB = (const float4*)((dir == 0 ? p : q) + (size_t)b * N_ * 4);

    // Build the A-embedding table: Aarr[j] = (x,y,z,1,-|a|^2/2,0,0,0).
    for (int j = threadIdx.x; j < N_; j += BLOCK) {
        float4 v = rowsA[j];
        _Float16 x = (_Float16)v.y, y = (_Float16)v.z, z = (_Float16)v.w;
        float xf = (float)x, yf = (float)y, zf = (float)z;
        float sq = fmaf(xf, xf, fmaf(yf, yf, zf * zf));
        half8 lo;
        lo[0] = x; lo[1] = y; lo[2] = z; lo[3] = (_Float16)1.0f;
        lo[4] = (_Float16)(-0.5f * sq);
        lo[5] = (_Float16)0.0f; lo[6] = (_Float16)0.0f; lo[7] = (_Float16)0.0f;
        Aarr[j] = lo;
    }

    // Per-wave B fragments: col-tiles 2W, 2W+1; each as LO (k=0..7 lanes)
    // and HI (k=8..15 lanes) variants.
    const int lane = threadIdx.x & 63;
    const int wid  = threadIdx.x >> 6;
    const int W    = blockIdx.x * WPB + wid;
    half8 bfLO[BFRAGS], bfHI[BFRAGS];
#pragma unroll
    for (int t = 0; t < BFRAGS; ++t) {
        float4 v = colsB[(W * BFRAGS + t) * 32 + (lane & 31)];
        _Float16 x = (_Float16)v.y, y = (_Float16)v.z, z = (_Float16)v.w;
        float xf = (float)x, yf = (float)y, zf = (float)z;
        float sq = fmaf(xf, xf, fmaf(yf, yf, zf * zf));
#pragma unroll
        for (int e = 0; e < 8; ++e) { bfLO[t][e] = (_Float16)0.0f; bfHI[t][e] = (_Float16)0.0f; }
        if (lane < 32) {
            bfLO[t][0] = x; bfLO[t][1] = y; bfLO[t][2] = z;
            bfLO[t][3] = (_Float16)(-0.5f * sq);
            bfLO[t][4] = (_Float16)1.0f;
        } else {
            bfHI[t][0] = x; bfHI[t][1] = y; bfHI[t][2] = z;
            bfHI[t][3] = (_Float16)(-0.5f * sq);
            bfHI[t][4] = (_Float16)1.0f;
        }
    }
    __syncthreads();

    floatx16 zero;
#pragma unroll
    for (int i = 0; i < 16; ++i) zero[i] = 0.0f;

    floatx16 accv0, accv1;
#pragma unroll
    for (int i = 0; i < 16; ++i) { accv0[i] = -3.4e38f; accv1[i] = -3.4e38f; }

    // Pipelined sweep: branch-free af prefetch (pad tile read at T=31,
    // never folded); 4-MFMA cluster at raised priority, folds at normal.
    half8 af = Aarr[lane];
#pragma unroll 1
    for (int T = 0; T < NPAIR; ++T) {
        half8 afn = Aarr[(T + 1) * 64 + lane];   // branch-free prefetch
        __builtin_amdgcn_s_setprio(1);
        floatx16 Ca0 = __builtin_amdgcn_mfma_f32_32x32x16_f16(af, bfLO[0], zero, 0, 0, 0);
        floatx16 Cb0 = __builtin_amdgcn_mfma_f32_32x32x16_f16(af, bfHI[0], zero, 0, 0, 0);
        floatx16 Ca1 = __builtin_amdgcn_mfma_f32_32x32x16_f16(af, bfLO[1], zero, 0, 0, 0);
        floatx16 Cb1 = __builtin_amdgcn_mfma_f32_32x32x16_f16(af, bfHI[1], zero, 0, 0, 0);
        __builtin_amdgcn_s_setprio(0);
#pragma unroll
        for (int i = 0; i < 16; ++i)
            accv0[i] = fmaxf(fmaxf(Ca0[i], Cb0[i]), accv0[i]);
#pragma unroll
        for (int i = 0; i < 16; ++i)
            accv1[i] = fmaxf(fmaxf(Ca1[i], Cb1[i]), accv1[i]);
        af = afn;
    }

    // Reduce the two 16-element accumulators to scalars (once per wave).
    float cmx0 = accv0[0], cmx1 = accv1[0];
#pragma unroll
    for (int i = 1; i < 16; ++i) {
        cmx0 = fmaxf(cmx0, accv0[i]);
        cmx1 = fmaxf(cmx1, accv1[i]);
    }

    // Combine the two lane-halves (each holds half the rows per column).
    cmx0 = fmaxf(cmx0, __shfl_xor(cmx0, 32, 64));
    cmx1 = fmaxf(cmx1, __shfl_xor(cmx1, 32, 64));

    float local = sqrtf(fmaxf(-2.0f * cmx0, 0.0f) + 1e-16f)
                + sqrtf(fmaxf(-2.0f * cmx1, 0.0f) + 1e-16f);

#pragma unroll
    for (int off = 32; off > 0; off >>= 1)
        local += __shfl_xor(local, off, 64);

    if (lane == 0) wsum[wid] = local;
    __syncthreads();
    if (threadIdx.x == 0) {
        float s = 0.0f;
#pragma unroll
        for (int w = 0; w < WPB; ++w) s += wsum[w];
        // 0.5 chamfer factor * 0.5 lane-dup; plain store, no init needed.
        partials[(blockIdx.z * B_ + blockIdx.y) * IBLK + blockIdx.x] = 0.25f * s;
    }
}

__global__ __launch_bounds__(RBLOCK) void chamfer_reduce_kernel(
    const float* __restrict__ partials, float* __restrict__ out)
{
    float v = fmaxf(0.0f, 0.0f);   // placate compiler; overwritten below
    v = partials[threadIdx.x] + partials[threadIdx.x + RBLOCK];
#pragma unroll
    for (int off = 32; off > 0; off >>= 1)
        v += __shfl_xor(v, off, 64);

    __shared__ float wsum[RBLOCK / 64];
    if ((threadIdx.x & 63) == 0) wsum[threadIdx.x >> 6] = v;
    __syncthreads();
    if (threadIdx.x == 0) {
        float s = 0.0f;
#pragma unroll
        for (int w = 0; w < RBLOCK / 64; ++w) s += wsum[w];
        out[0] = s;
    }
}

extern "C" void kernel_launch(void* const* d_in, const int* in_sizes, int n_in,
                              void* d_out, int out_size, void* d_ws, size_t ws_size,
                              hipStream_t stream) {
    const float* p = (const float*)d_in[0];
    const float* q = (const float*)d_in[1];
    float* out = (float*)d_out;
    float* partials = (float*)d_ws;

    dim3 grid(IBLK, B_, 2);                 // 4 x 64 x 2 = 512 blocks
    chamfer_mfma_kernel<<<grid, BLOCK, 0, stream>>>(p, q, partials);
    chamfer_reduce_kernel<<<1, RBLOCK, 0, stream>>>(partials, out);
}